// Round 1
// baseline (555.879 us; speedup 1.0000x reference)
//
#include <hip/hip_runtime.h>

typedef short  bf16x8 __attribute__((ext_vector_type(8)));
typedef float  f32x4  __attribute__((ext_vector_type(4)));

__device__ __forceinline__ ushort f2b(float f) {
    union { float f; unsigned u; } c; c.f = f;
    unsigned r = c.u + 0x7fffu + ((c.u >> 16) & 1u);
    return (ushort)(r >> 16);
}

// ---------------------------------------------------------------- cast x -> bf16
__global__ __launch_bounds__(256) void cast_f32_bf16(const float* __restrict__ in,
                                                     ushort* __restrict__ out, int n) {
    for (int i = (blockIdx.x * blockDim.x + threadIdx.x) * 4; i < n;
         i += gridDim.x * blockDim.x * 4) {
        float4 v = *(const float4*)(in + i);
        ushort4 o;
        o.x = f2b(v.x); o.y = f2b(v.y); o.z = f2b(v.z); o.w = f2b(v.w);
        *(ushort4*)(out + i) = o;
    }
}

// ------------------------------------------- transpose + cast: W[R][C] f32 -> WT[C][R] bf16
__global__ __launch_bounds__(256) void transpose_cast(const float* __restrict__ in,
                                                      ushort* __restrict__ out, int R, int C) {
    __shared__ float tile[32][33];
    int c0 = blockIdx.x * 32, r0 = blockIdx.y * 32;
    int tx = threadIdx.x, ty = threadIdx.y;
#pragma unroll
    for (int i = 0; i < 32; i += 8)
        tile[ty + i][tx] = in[(size_t)(r0 + ty + i) * C + c0 + tx];
    __syncthreads();
#pragma unroll
    for (int i = 0; i < 32; i += 8)
        out[(size_t)(c0 + ty + i) * R + r0 + tx] = f2b(tile[tx][ty + i]);
}

// --------------------------------------------------- VT[b][d][s] = kvb[b,s, 64+d]  (bf16)
__global__ __launch_bounds__(256) void transpose_v(const ushort* __restrict__ kvb,
                                                   ushort* __restrict__ vt) {
    __shared__ ushort tile[32][33];
    int b = blockIdx.z;
    int s0 = blockIdx.x * 32, d0 = blockIdx.y * 32;
    int tx = threadIdx.x, ty = threadIdx.y;
#pragma unroll
    for (int i = 0; i < 32; i += 8)
        tile[ty + i][tx] = kvb[(size_t)(b * 2048 + s0 + ty + i) * 128 + 64 + d0 + tx];
    __syncthreads();
#pragma unroll
    for (int i = 0; i < 32; i += 8)
        vt[(size_t)(b * 64 + d0 + ty + i) * 2048 + s0 + tx] = tile[tx][ty + i];
}

__global__ void concat_bias(const float* __restrict__ bk, const float* __restrict__ bv,
                            float* __restrict__ o) {
    int i = threadIdx.x;
    if (i < 128) o[i] = (i < 64) ? bk[i] : bv[i - 64];
}

// ---------------------------------------------------------------- GEMM: Y = A @ BT^T + bias
// A:[M][K] bf16 row-major, BT:[N][K] bf16 row-major (i.e. B transposed), Y:[M][N]
// 128x128 tile, 256 threads (4 waves in 2x2), each wave 64x64 = 4x4 frags of 16x16.
template <bool OUT_BF16>
__global__ __launch_bounds__(256) void gemm_bt(const ushort* __restrict__ A,
                                               const ushort* __restrict__ BT,
                                               const float* __restrict__ bias,
                                               void* __restrict__ Y, int M, int N, int K) {
    __shared__ alignas(16) ushort As[128][72];  // 64 + 8 pad -> 144B rows (16B aligned)
    __shared__ alignas(16) ushort Bs[128][72];

    int m0 = blockIdx.y * 128, n0 = blockIdx.x * 128;
    int t = threadIdx.x;
    int lane = t & 63, wid = t >> 6;
    int wr = wid >> 1, wc = wid & 1;
    int fr = lane & 15, fg = lane >> 4;

    f32x4 acc[4][4] = {};

    for (int kb = 0; kb < K; kb += 64) {
        // stage A & B tiles (128x64 bf16 each) via registers
#pragma unroll
        for (int i = 0; i < 4; i++) {
            int chunk = t + i * 256;          // 0..1023
            int row = chunk >> 3, kc = chunk & 7;
            *(uint4*)&As[row][kc * 8] =
                *(const uint4*)(A + (size_t)(m0 + row) * K + kb + kc * 8);
            *(uint4*)&Bs[row][kc * 8] =
                *(const uint4*)(BT + (size_t)(n0 + row) * K + kb + kc * 8);
        }
        __syncthreads();
#pragma unroll
        for (int kk = 0; kk < 2; kk++) {
            bf16x8 af[4], bfr[4];
#pragma unroll
            for (int m = 0; m < 4; m++)
                af[m] = *(const bf16x8*)&As[wr * 64 + m * 16 + fr][kk * 32 + fg * 8];
#pragma unroll
            for (int n = 0; n < 4; n++)
                bfr[n] = *(const bf16x8*)&Bs[wc * 64 + n * 16 + fr][kk * 32 + fg * 8];
#pragma unroll
            for (int m = 0; m < 4; m++)
#pragma unroll
                for (int n = 0; n < 4; n++)
                    acc[m][n] = __builtin_amdgcn_mfma_f32_16x16x32_bf16(
                        af[m], bfr[n], acc[m][n], 0, 0, 0);
        }
        __syncthreads();
    }

#pragma unroll
    for (int m = 0; m < 4; m++)
#pragma unroll
        for (int n = 0; n < 4; n++) {
            int col = n0 + wc * 64 + n * 16 + fr;
            float bv = bias ? bias[col] : 0.f;
#pragma unroll
            for (int j = 0; j < 4; j++) {
                int row = m0 + wr * 64 + m * 16 + fg * 4 + j;
                float v = acc[m][n][j] + bv;
                if (OUT_BF16)
                    ((ushort*)Y)[(size_t)row * N + col] = f2b(v);
                else
                    ((float*)Y)[(size_t)row * N + col] = v;
            }
        }
}

// ---------------------------------------------------------------- flash attention
// grid: (S/64, H, B), block 256 (4 waves). Wave w: 16 q-rows. KV tiles of 32.
// qb:[B*S][1024] bf16, kvb:[B*S][128] bf16 (cols 0-63 K, 64-127 V), vt:[B*64][2048] bf16
// ctx:[B*S][1024] bf16
__global__ __launch_bounds__(256) void attn_kernel(const ushort* __restrict__ qb,
                                                   const ushort* __restrict__ kvb,
                                                   const ushort* __restrict__ vt,
                                                   ushort* __restrict__ ctx) {
    const int S = 2048, E = 1024, D = 64;
    int b = blockIdx.z, h = blockIdx.y;
    int wid = threadIdx.x >> 6, lane = threadIdx.x & 63;
    int q0 = blockIdx.x * 64 + wid * 16;
    int fr = lane & 15, fg = lane >> 4;

    __shared__ alignas(16) ushort plds[4][16][40];  // per-wave P tile, 80B rows

    // Q fragments (16 rows x 64 d), hoisted
    const ushort* qbase = qb + (size_t)(b * S + q0 + fr) * E + h * D;
    bf16x8 qf0 = *(const bf16x8*)(qbase + fg * 8);
    bf16x8 qf1 = *(const bf16x8*)(qbase + 32 + fg * 8);

    f32x4 acc[4] = {};
    float m_run[4], l_run[4];
#pragma unroll
    for (int j = 0; j < 4; j++) { m_run[j] = -1e30f; l_run[j] = 0.f; }
    const float sc = 0.125f;  // 1/sqrt(64)

    for (int s0 = 0; s0 < S; s0 += 32) {
        // ---- S = Q K^T for 16 q-rows x 32 kv-cols
        f32x4 sfr[2] = {};
#pragma unroll
        for (int n = 0; n < 2; n++) {
            const ushort* kb = kvb + (size_t)(b * S + s0 + n * 16 + fr) * 128;
            bf16x8 k0 = *(const bf16x8*)(kb + fg * 8);
            bf16x8 k1 = *(const bf16x8*)(kb + 32 + fg * 8);
            sfr[n] = __builtin_amdgcn_mfma_f32_16x16x32_bf16(qf0, k0, sfr[n], 0, 0, 0);
            sfr[n] = __builtin_amdgcn_mfma_f32_16x16x32_bf16(qf1, k1, sfr[n], 0, 0, 0);
        }
        // ---- online softmax (rows live in 16-lane groups, 4 rows/lane as regs j)
        float f[4];
#pragma unroll
        for (int j = 0; j < 4; j++) {
            float t0 = sfr[0][j] * sc, t1 = sfr[1][j] * sc;
            float mx = fmaxf(t0, t1);
            mx = fmaxf(mx, __shfl_xor(mx, 1));
            mx = fmaxf(mx, __shfl_xor(mx, 2));
            mx = fmaxf(mx, __shfl_xor(mx, 4));
            mx = fmaxf(mx, __shfl_xor(mx, 8));
            float mnew = fmaxf(m_run[j], mx);
            f[j] = __expf(m_run[j] - mnew);
            float p0 = __expf(t0 - mnew);
            float p1 = __expf(t1 - mnew);
            sfr[0][j] = p0; sfr[1][j] = p1;
            float s = p0 + p1;
            s += __shfl_xor(s, 1);
            s += __shfl_xor(s, 2);
            s += __shfl_xor(s, 4);
            s += __shfl_xor(s, 8);
            l_run[j] = l_run[j] * f[j] + s;
            m_run[j] = mnew;
        }
#pragma unroll
        for (int dn = 0; dn < 4; dn++)
#pragma unroll
            for (int j = 0; j < 4; j++) acc[dn][j] *= f[j];
        // ---- P -> LDS (bf16), then read back as PV A-fragment
#pragma unroll
        for (int n = 0; n < 2; n++)
#pragma unroll
            for (int j = 0; j < 4; j++)
                plds[wid][fg * 4 + j][n * 16 + fr] = f2b(sfr[n][j]);
        asm volatile("s_waitcnt lgkmcnt(0)" ::: "memory");
        __builtin_amdgcn_sched_barrier(0);
        bf16x8 pa = *(const bf16x8*)&plds[wid][fr][fg * 8];
        // ---- O += P V   (V via VT so B-frags are contiguous)
#pragma unroll
        for (int dn = 0; dn < 4; dn++) {
            const ushort* vb = vt + (size_t)(b * 64 + dn * 16 + fr) * S + s0 + fg * 8;
            bf16x8 v = *(const bf16x8*)vb;
            acc[dn] = __builtin_amdgcn_mfma_f32_16x16x32_bf16(pa, v, acc[dn], 0, 0, 0);
        }
    }
    // ---- epilogue: normalize and store
    ushort* obase = ctx + (size_t)(b * S + q0) * E + h * D;
#pragma unroll
    for (int dn = 0; dn < 4; dn++)
#pragma unroll
        for (int j = 0; j < 4; j++) {
            float v = acc[dn][j] / l_run[j];
            obase[(size_t)(fg * 4 + j) * E + dn * 16 + fr] = f2b(v);
        }
}

// ---------------------------------------------------------------- launch
extern "C" void kernel_launch(void* const* d_in, const int* in_sizes, int n_in,
                              void* d_out, int out_size, void* d_ws, size_t ws_size,
                              hipStream_t stream) {
    const int B = 4, S = 2048, E = 1024, D = 64;
    const int M = B * S;  // 8192

    const float* x  = (const float*)d_in[0];
    const float* Wq = (const float*)d_in[1];
    const float* bq = (const float*)d_in[2];
    const float* Wk = (const float*)d_in[3];
    const float* bk = (const float*)d_in[4];
    const float* Wv = (const float*)d_in[5];
    const float* bv = (const float*)d_in[6];
    const float* Wo = (const float*)d_in[7];
    const float* bo = (const float*)d_in[8];
    float* out = (float*)d_out;

    char* w = (char*)d_ws;
    ushort* xb   = (ushort*)w;                 w += (size_t)M * E * 2;      // 16.8 MB
    ushort* qb   = (ushort*)w;                 w += (size_t)M * E * 2;      // 16.8 MB
    ushort* ctx  = (ushort*)w;                 w += (size_t)M * E * 2;      // 16.8 MB
    ushort* WqT  = (ushort*)w;                 w += (size_t)E * E * 2;      // 2 MB
    ushort* WoT  = (ushort*)w;                 w += (size_t)E * E * 2;      // 2 MB
    ushort* WkvT = (ushort*)w;                 w += (size_t)128 * E * 2;    // 0.26 MB
    ushort* kvb  = (ushort*)w;                 w += (size_t)M * 128 * 2;    // 2.1 MB
    ushort* vtb  = (ushort*)w;                 w += (size_t)B * D * S * 2;  // 1.05 MB
    float*  bkv  = (float*)w;                  w += 512;

    // prep
    cast_f32_bf16<<<2048, 256, 0, stream>>>(x, xb, M * E);
    transpose_cast<<<dim3(32, 32), dim3(32, 8), 0, stream>>>(Wq, WqT, E, E);
    transpose_cast<<<dim3(2, 32),  dim3(32, 8), 0, stream>>>(Wk, WkvT, E, D);
    transpose_cast<<<dim3(2, 32),  dim3(32, 8), 0, stream>>>(Wv, WkvT + (size_t)64 * E, E, D);
    transpose_cast<<<dim3(32, 32), dim3(32, 8), 0, stream>>>(Wo, WoT, E, E);
    concat_bias<<<1, 128, 0, stream>>>(bk, bv, bkv);

    // projections
    gemm_bt<true><<<dim3(E / 128, M / 128), 256, 0, stream>>>(xb, WqT, bq, qb, M, E, E);
    gemm_bt<true><<<dim3(1, M / 128), 256, 0, stream>>>(xb, WkvT, bkv, kvb, M, 128, E);
    transpose_v<<<dim3(S / 32, 2, B), dim3(32, 8), 0, stream>>>(kvb, vtb);

    // attention
    attn_kernel<<<dim3(S / 64, 16, B), 256, 0, stream>>>(qb, kvb, vtb, ctx);

    // output projection (fp32 out)
    gemm_bt<false><<<dim3(E / 128, M / 128), 256, 0, stream>>>(ctx, WoT, bo, (void*)out, M, E, E);
}

// Round 2
// 352.955 us; speedup vs baseline: 1.5749x; 1.5749x over previous
//
#include <hip/hip_runtime.h>

typedef short  bf16x8 __attribute__((ext_vector_type(8)));
typedef float  f32x4  __attribute__((ext_vector_type(4)));
typedef float  f32x16 __attribute__((ext_vector_type(16)));

__device__ __forceinline__ ushort f2b(float f) {
    union { float f; unsigned u; } c; c.f = f;
    unsigned r = c.u + 0x7fffu + ((c.u >> 16) & 1u);
    return (ushort)(r >> 16);
}

__device__ __forceinline__ unsigned cvtpk(float lo, float hi) {
    unsigned r;
    asm("v_cvt_pk_bf16_f32 %0, %1, %2" : "=v"(r) : "v"(lo), "v"(hi));
    return r;
}

// ---------------------------------------------------------------- cast x -> bf16
__global__ __launch_bounds__(256) void cast_f32_bf16(const float* __restrict__ in,
                                                     ushort* __restrict__ out, int n) {
    for (int i = (blockIdx.x * blockDim.x + threadIdx.x) * 4; i < n;
         i += gridDim.x * blockDim.x * 4) {
        float4 v = *(const float4*)(in + i);
        ushort4 o;
        o.x = f2b(v.x); o.y = f2b(v.y); o.z = f2b(v.z); o.w = f2b(v.w);
        *(ushort4*)(out + i) = o;
    }
}

// ------------------------------------------- transpose + cast: W[R][C] f32 -> WT[C][R] bf16
__global__ __launch_bounds__(256) void transpose_cast(const float* __restrict__ in,
                                                      ushort* __restrict__ out, int R, int C) {
    __shared__ float tile[32][33];
    int c0 = blockIdx.x * 32, r0 = blockIdx.y * 32;
    int tx = threadIdx.x, ty = threadIdx.y;
#pragma unroll
    for (int i = 0; i < 32; i += 8)
        tile[ty + i][tx] = in[(size_t)(r0 + ty + i) * C + c0 + tx];
    __syncthreads();
#pragma unroll
    for (int i = 0; i < 32; i += 8)
        out[(size_t)(c0 + ty + i) * R + r0 + tx] = f2b(tile[tx][ty + i]);
}

// --------------------------------------------------- VT[b][d][s] = kvb[b,s, 64+d]  (bf16)
__global__ __launch_bounds__(256) void transpose_v(const ushort* __restrict__ kvb,
                                                   ushort* __restrict__ vt) {
    __shared__ ushort tile[32][33];
    int b = blockIdx.z;
    int s0 = blockIdx.x * 32, d0 = blockIdx.y * 32;
    int tx = threadIdx.x, ty = threadIdx.y;
#pragma unroll
    for (int i = 0; i < 32; i += 8)
        tile[ty + i][tx] = kvb[(size_t)(b * 2048 + s0 + ty + i) * 128 + 64 + d0 + tx];
    __syncthreads();
#pragma unroll
    for (int i = 0; i < 32; i += 8)
        vt[(size_t)(b * 64 + d0 + ty + i) * 2048 + s0 + tx] = tile[tx][ty + i];
}

__global__ void concat_bias(const float* __restrict__ bk, const float* __restrict__ bv,
                            float* __restrict__ o) {
    int i = threadIdx.x;
    if (i < 128) o[i] = (i < 64) ? bk[i] : bv[i - 64];
}

// ---------------------------------------------------------------- GEMM: Y = A @ BT^T + bias
template <bool OUT_BF16>
__global__ __launch_bounds__(256) void gemm_bt(const ushort* __restrict__ A,
                                               const ushort* __restrict__ BT,
                                               const float* __restrict__ bias,
                                               void* __restrict__ Y, int M, int N, int K) {
    __shared__ alignas(16) ushort As[128][72];
    __shared__ alignas(16) ushort Bs[128][72];

    int m0 = blockIdx.y * 128, n0 = blockIdx.x * 128;
    int t = threadIdx.x;
    int lane = t & 63, wid = t >> 6;
    int wr = wid >> 1, wc = wid & 1;
    int fr = lane & 15, fg = lane >> 4;

    f32x4 acc[4][4] = {};

    for (int kb = 0; kb < K; kb += 64) {
#pragma unroll
        for (int i = 0; i < 4; i++) {
            int chunk = t + i * 256;
            int row = chunk >> 3, kc = chunk & 7;
            *(uint4*)&As[row][kc * 8] =
                *(const uint4*)(A + (size_t)(m0 + row) * K + kb + kc * 8);
            *(uint4*)&Bs[row][kc * 8] =
                *(const uint4*)(BT + (size_t)(n0 + row) * K + kb + kc * 8);
        }
        __syncthreads();
#pragma unroll
        for (int kk = 0; kk < 2; kk++) {
            bf16x8 af[4], bfr[4];
#pragma unroll
            for (int m = 0; m < 4; m++)
                af[m] = *(const bf16x8*)&As[wr * 64 + m * 16 + fr][kk * 32 + fg * 8];
#pragma unroll
            for (int n = 0; n < 4; n++)
                bfr[n] = *(const bf16x8*)&Bs[wc * 64 + n * 16 + fr][kk * 32 + fg * 8];
#pragma unroll
            for (int m = 0; m < 4; m++)
#pragma unroll
                for (int n = 0; n < 4; n++)
                    acc[m][n] = __builtin_amdgcn_mfma_f32_16x16x32_bf16(
                        af[m], bfr[n], acc[m][n], 0, 0, 0);
        }
        __syncthreads();
    }

#pragma unroll
    for (int m = 0; m < 4; m++)
#pragma unroll
        for (int n = 0; n < 4; n++) {
            int col = n0 + wc * 64 + n * 16 + fr;
            float bv = bias ? bias[col] : 0.f;
#pragma unroll
            for (int j = 0; j < 4; j++) {
                int row = m0 + wr * 64 + m * 16 + fg * 4 + j;
                float v = acc[m][n][j] + bv;
                if (OUT_BF16)
                    ((ushort*)Y)[(size_t)row * N + col] = f2b(v);
                else
                    ((float*)Y)[(size_t)row * N + col] = v;
            }
        }
}

// ---------------------------------------------------------------- flash attention v2
// Swapped-QK 32x32x16 structure: per wave 32 q-rows, KVBLK=64, softmax in-register,
// P->PV operand via cvt_pk_bf16 + permlane32_swap, O accumulated transposed (O^T = VT * P^T)
// so softmax state (m,l) is per-lane (col = q = lane&31).
// grid: (S/128, H, B), block 256 (4 waves).
__global__ __launch_bounds__(256, 4) void attn_kernel(const ushort* __restrict__ qb,
                                                      const ushort* __restrict__ kvb,
                                                      const ushort* __restrict__ vt,
                                                      ushort* __restrict__ ctx) {
    const int S = 2048, E = 1024;
    int b = blockIdx.z, h = blockIdx.y;
    int wid = threadIdx.x >> 6, lane = threadIdx.x & 63;
    int q0 = blockIdx.x * 128 + wid * 32;
    int ql = lane & 31, hi = lane >> 5;

    const float sc2 = 0.18033688011112042f;  // (1/sqrt(64)) * log2(e)

    // Q fragments: B-operand rows, lane ql row, d = s*16 + hi*8 + i
    const ushort* qbase = qb + (size_t)(b * S + q0 + ql) * E + h * 64 + hi * 8;
    bf16x8 qf0 = *(const bf16x8*)(qbase);
    bf16x8 qf1 = *(const bf16x8*)(qbase + 16);
    bf16x8 qf2 = *(const bf16x8*)(qbase + 32);
    bf16x8 qf3 = *(const bf16x8*)(qbase + 48);

    f32x16 acc0 = {}, acc1 = {};      // O^T tiles: d0=0 / d0=32; col=q, row=d
    float m_run = -1e30f, l_run = 0.f;

    const ushort* kptr = kvb + (size_t)(b * S + ql) * 128 + hi * 8;        // K rows
    const ushort* vp0  = vt + (size_t)(b * 64 + ql) * S + hi * 8;          // VT rows d0=0
    const ushort* vp1  = vp0 + (size_t)32 * S;                             // VT rows d0=32

    for (int s0 = 0; s0 < S; s0 += 64, kptr += 64 * 128) {
        // ---- S^T = K Q^T : two 32x32 k-tiles, K-dim = 64 (4 slices of 16)
        f32x16 pt0 = {}, pt1 = {};
#pragma unroll
        for (int s = 0; s < 4; s++) {
            bf16x8 kf = *(const bf16x8*)(kptr + s * 16);
            bf16x8 qs = (s == 0) ? qf0 : (s == 1) ? qf1 : (s == 2) ? qf2 : qf3;
            pt0 = __builtin_amdgcn_mfma_f32_32x32x16_bf16(kf, qs, pt0, 0, 0, 0);
        }
#pragma unroll
        for (int s = 0; s < 4; s++) {
            bf16x8 kf = *(const bf16x8*)(kptr + 32 * 128 + s * 16);
            bf16x8 qs = (s == 0) ? qf0 : (s == 1) ? qf1 : (s == 2) ? qf2 : qf3;
            pt1 = __builtin_amdgcn_mfma_f32_32x32x16_bf16(kf, qs, pt1, 0, 0, 0);
        }

        // ---- online softmax (in-register; lane holds 32 of 64 k's for q=ql)
        float v[16];
#pragma unroll
        for (int r = 0; r < 16; r++) v[r] = fmaxf(pt0[r], pt1[r]);
#pragma unroll
        for (int st = 8; st; st >>= 1)
#pragma unroll
            for (int r = 0; r < 8; r++)
                if (r < st) v[r] = fmaxf(v[r], v[r + st]);
        float mx = fmaxf(v[0], __shfl_xor(v[0], 32));
        float mx2 = mx * sc2;

        if (__any(mx2 > m_run + 11.5f)) {   // defer-max (T13), log2 units
            float mnew = fmaxf(m_run, mx2);
            float f = exp2f(m_run - mnew);
            l_run *= f;
            acc0 = acc0 * f;
            acc1 = acc1 * f;
            m_run = mnew;
        }
        float nm = -m_run;
#pragma unroll
        for (int r = 0; r < 16; r++) pt0[r] = exp2f(fmaf(pt0[r], sc2, nm));
#pragma unroll
        for (int r = 0; r < 16; r++) pt1[r] = exp2f(fmaf(pt1[r], sc2, nm));
#pragma unroll
        for (int r = 0; r < 16; r++) v[r] = pt0[r] + pt1[r];
#pragma unroll
        for (int st = 8; st; st >>= 1)
#pragma unroll
            for (int r = 0; r < 8; r++)
                if (r < st) v[r] = v[r] + v[r + st];
        l_run += v[0] + __shfl_xor(v[0], 32);

        // ---- PV: O^T += VT * P^T, 4 k-slices of 16
#pragma unroll
        for (int ks = 0; ks < 4; ks++) {
            float p0, p1, p2, p3, p4, p5, p6, p7;
            if (ks == 0)      { p0=pt0[0]; p1=pt0[1]; p2=pt0[2]; p3=pt0[3];
                                p4=pt0[4]; p5=pt0[5]; p6=pt0[6]; p7=pt0[7]; }
            else if (ks == 1) { p0=pt0[8]; p1=pt0[9]; p2=pt0[10]; p3=pt0[11];
                                p4=pt0[12]; p5=pt0[13]; p6=pt0[14]; p7=pt0[15]; }
            else if (ks == 2) { p0=pt1[0]; p1=pt1[1]; p2=pt1[2]; p3=pt1[3];
                                p4=pt1[4]; p5=pt1[5]; p6=pt1[6]; p7=pt1[7]; }
            else              { p0=pt1[8]; p1=pt1[9]; p2=pt1[10]; p3=pt1[11];
                                p4=pt1[12]; p5=pt1[13]; p6=pt1[14]; p7=pt1[15]; }
            unsigned w0 = cvtpk(p0, p1);
            unsigned w2 = cvtpk(p4, p5);
            asm volatile("v_permlane32_swap_b32 %0, %1" : "+v"(w0), "+v"(w2));
            unsigned w1 = cvtpk(p2, p3);
            unsigned w3 = cvtpk(p6, p7);
            asm volatile("v_permlane32_swap_b32 %0, %1" : "+v"(w1), "+v"(w3));
            bf16x8 pa;
            ((unsigned*)&pa)[0] = w0;
            ((unsigned*)&pa)[1] = w1;
            ((unsigned*)&pa)[2] = w2;
            ((unsigned*)&pa)[3] = w3;

            bf16x8 va0 = *(const bf16x8*)(vp0 + s0 + ks * 16);
            bf16x8 va1 = *(const bf16x8*)(vp1 + s0 + ks * 16);
            acc0 = __builtin_amdgcn_mfma_f32_32x32x16_bf16(va0, pa, acc0, 0, 0, 0);
            acc1 = __builtin_amdgcn_mfma_f32_32x32x16_bf16(va1, pa, acc1, 0, 0, 0);
        }
    }

    // ---- epilogue: O[q][d] = acc[d-row][q-col] / l_run ; lane owns q=ql, d = crow(reg,hi)
    float inv = 1.f / l_run;
    ushort* obase = ctx + (size_t)(b * S + q0 + ql) * E + h * 64;
#pragma unroll
    for (int g = 0; g < 4; g++) {
        int d = 8 * g + 4 * hi;
        ushort4 o;
        o.x = f2b(acc0[4 * g + 0] * inv);
        o.y = f2b(acc0[4 * g + 1] * inv);
        o.z = f2b(acc0[4 * g + 2] * inv);
        o.w = f2b(acc0[4 * g + 3] * inv);
        *(ushort4*)(obase + d) = o;
    }
#pragma unroll
    for (int g = 0; g < 4; g++) {
        int d = 32 + 8 * g + 4 * hi;
        ushort4 o;
        o.x = f2b(acc1[4 * g + 0] * inv);
        o.y = f2b(acc1[4 * g + 1] * inv);
        o.z = f2b(acc1[4 * g + 2] * inv);
        o.w = f2b(acc1[4 * g + 3] * inv);
        *(ushort4*)(obase + d) = o;
    }
}

// ---------------------------------------------------------------- launch
extern "C" void kernel_launch(void* const* d_in, const int* in_sizes, int n_in,
                              void* d_out, int out_size, void* d_ws, size_t ws_size,
                              hipStream_t stream) {
    const int B = 4, S = 2048, E = 1024, D = 64;
    const int M = B * S;  // 8192

    const float* x  = (const float*)d_in[0];
    const float* Wq = (const float*)d_in[1];
    const float* bq = (const float*)d_in[2];
    const float* Wk = (const float*)d_in[3];
    const float* bk = (const float*)d_in[4];
    const float* Wv = (const float*)d_in[5];
    const float* bv = (const float*)d_in[6];
    const float* Wo = (const float*)d_in[7];
    const float* bo = (const float*)d_in[8];
    float* out = (float*)d_out;

    char* w = (char*)d_ws;
    ushort* xb   = (ushort*)w;                 w += (size_t)M * E * 2;
    ushort* qb   = (ushort*)w;                 w += (size_t)M * E * 2;
    ushort* ctx  = (ushort*)w;                 w += (size_t)M * E * 2;
    ushort* WqT  = (ushort*)w;                 w += (size_t)E * E * 2;
    ushort* WoT  = (ushort*)w;                 w += (size_t)E * E * 2;
    ushort* WkvT = (ushort*)w;                 w += (size_t)128 * E * 2;
    ushort* kvb  = (ushort*)w;                 w += (size_t)M * 128 * 2;
    ushort* vtb  = (ushort*)w;                 w += (size_t)B * D * S * 2;
    float*  bkv  = (float*)w;                  w += 512;

    // prep
    cast_f32_bf16<<<2048, 256, 0, stream>>>(x, xb, M * E);
    transpose_cast<<<dim3(32, 32), dim3(32, 8), 0, stream>>>(Wq, WqT, E, E);
    transpose_cast<<<dim3(2, 32),  dim3(32, 8), 0, stream>>>(Wk, WkvT, E, D);
    transpose_cast<<<dim3(2, 32),  dim3(32, 8), 0, stream>>>(Wv, WkvT + (size_t)64 * E, E, D);
    transpose_cast<<<dim3(32, 32), dim3(32, 8), 0, stream>>>(Wo, WoT, E, E);
    concat_bias<<<1, 128, 0, stream>>>(bk, bv, bkv);

    // projections
    gemm_bt<true><<<dim3(E / 128, M / 128), 256, 0, stream>>>(xb, WqT, bq, qb, M, E, E);
    gemm_bt<true><<<dim3(1, M / 128), 256, 0, stream>>>(xb, WkvT, bkv, kvb, M, 128, E);
    transpose_v<<<dim3(S / 32, 2, B), dim3(32, 8), 0, stream>>>(kvb, vtb);

    // attention
    attn_kernel<<<dim3(S / 128, 16, B), 256, 0, stream>>>(qb, kvb, vtb, ctx);

    // output projection (fp32 out)
    gemm_bt<false><<<dim3(E / 128, M / 128), 256, 0, stream>>>(ctx, WoT, bo, (void*)out, M, E, E);
}